// Round 13
// baseline (349.138 us; speedup 1.0000x reference)
//
#include <hip/hip_runtime.h>
#include <cstdint>
#include <cstddef>

#define BATCH 4096
#define HID   2048

typedef __attribute__((ext_vector_type(8))) short bf16x8;
typedef __attribute__((ext_vector_type(4))) float f32x4;
typedef __attribute__((ext_vector_type(16))) float f32x16;

__device__ __forceinline__ unsigned short f2bf(float f) {
  union { float f; unsigned u; } a; a.f = f;
  unsigned u = a.u;
  return (unsigned short)((u + 0x7FFFu + ((u >> 16) & 1u)) >> 16);  // RNE
}

__device__ __forceinline__ void gload_lds16(const void* g, void* l) {
  __builtin_amdgcn_global_load_lds((const __attribute__((address_space(1))) void*)g,
                                   (__attribute__((address_space(3))) void*)l, 16, 0, 0);
}

#define SCHED0() __builtin_amdgcn_sched_barrier(0)
#define SBAR()  do { SCHED0(); __builtin_amdgcn_s_barrier(); SCHED0(); } while (0)
#define WAITV(N) do { SCHED0(); asm volatile("s_waitcnt vmcnt(" #N ")" ::: "memory"); SCHED0(); } while (0)
#define WAITL(N) do { SCHED0(); asm volatile("s_waitcnt lgkmcnt(" #N ")" ::: "memory"); SCHED0(); } while (0)
#define DSR(dst, adr, IMM) asm volatile("ds_read_b128 %0, %1 offset:" #IMM : "=v"(dst) : "v"(adr))
#define PRIO1() __builtin_amdgcn_s_setprio(1)
#define PRIO0() __builtin_amdgcn_s_setprio(0)

// 12 ds_read_b128 for group c+1: A frags AS[2mf+k] (2 mf x 2 kstep),
// B frags BS[2g+k] (4 gates x 2 kstep). kstep flips addr bit5 (chunk XOR trick).
#define RD12(AS, BS) do { \
  unsigned a0_ = adrA + (unsigned)o_n, a1_ = a0_ ^ 32u; \
  unsigned b0_ = adrB + (unsigned)o_n, b1_ = b0_ ^ 32u; \
  DSR(AS[0],a0_,0);    DSR(AS[1],a1_,0);    DSR(AS[2],a0_,2048); DSR(AS[3],a1_,2048); \
  DSR(BS[0],b0_,0);    DSR(BS[1],b1_,0);    DSR(BS[2],b0_,2048); DSR(BS[3],b1_,2048); \
  DSR(BS[4],b0_,4096); DSR(BS[5],b1_,4096); DSR(BS[6],b0_,6144); DSR(BS[7],b1_,6144); \
} while (0)

// 16 MFMA 32x32x16: 2 M-frags x 4 gate-frags, 2 ksteps chained per acc
#define MFMA16(AS, BS) do { _Pragma("unroll") \
  for (int mf_ = 0; mf_ < 2; mf_++) { _Pragma("unroll") \
    for (int g_ = 0; g_ < 4; g_++) { \
      acc[mf_][g_] = __builtin_amdgcn_mfma_f32_32x32x16_bf16(AS[2*mf_],   BS[2*g_],   acc[mf_][g_], 0, 0, 0); \
      acc[mf_][g_] = __builtin_amdgcn_mfma_f32_32x32x16_bf16(AS[2*mf_+1], BS[2*g_+1], acc[mf_][g_], 0, 0, 0); \
    } } } while (0)

// stage one 32KB group (A 256x32K + B 256x32K) into region offset DOF; 4 gloads/thread
#define STAGE_G(KOFF, DOF) do { \
  gload_lds16(pA + (KOFF),          dD + (DOF)); \
  gload_lds16(pA + 524288 + (KOFF), dD + (DOF) + 8192); \
  gload_lds16(pB + (KOFF),          dD + (DOF) + 16384); \
  gload_lds16(pB + 131072 + (KOFF), dD + (DOF) + 24576); } while (0)

#define ADVR(o) do { (o) = ((o) + 32768) & 131071; } while (0)

// slot c: drain stage(c+1) [VW], barrier, prev reads done [lgkm0, free],
// issue reads(c+1) + stage(c+3), then 16 MFMAs on group c (prev-slot regs).
#define SLOT(VW, STG, ACUR, BCUR, ANXT, BNXT) do { \
  VW; \
  SBAR(); \
  WAITL(0); \
  RD12(ANXT, BNXT); \
  STG; \
  SCHED0(); \
  PRIO1(); MFMA16(ACUR, BCUR); PRIO0(); \
  ADVR(o_n); ADVR(o_s); koff += 32; \
} while (0)

// ---- fp32 -> bf16 pack (verified r2): A=[x|h] 4096x4096; Wbf gate-major 8192x4096
__global__ __launch_bounds__(256) void convert_kernel(
    const float* __restrict__ x, const float* __restrict__ h,
    const float* __restrict__ wii, const float* __restrict__ wif,
    const float* __restrict__ wig, const float* __restrict__ wio,
    const float* __restrict__ whi, const float* __restrict__ whf,
    const float* __restrict__ whg, const float* __restrict__ who,
    unsigned short* __restrict__ Abf, unsigned short* __restrict__ Wbf) {
  int seg = blockIdx.y;
  const float* src;
  unsigned short* dst;
  int ofs;
  size_t rofs;
  if (seg < 4) {
    src = (seg < 2) ? x : h;
    dst = Abf;
    ofs = (seg < 2) ? 0 : 2048;
    rofs = (seg & 1) ? 2048 : 0;
    src += rofs * 2048;
  } else {
    int g = (seg - 4) & 3;
    dst = Wbf + (size_t)g * 2048 * 4096;
    ofs = (seg >= 8) ? 2048 : 0;
    rofs = 0;
    switch (seg) {
      case 4: src = wii; break; case 5: src = wif; break;
      case 6: src = wig; break; case 7: src = wio; break;
      case 8: src = whi; break; case 9: src = whf; break;
      case 10: src = whg; break; default: src = who; break;
    }
  }
  size_t idx = (size_t)blockIdx.x * 256 + threadIdx.x;
  size_t e = idx * 4;
  int n = (int)(e >> 11);
  int k = (int)(e & 2047);
  float4 v = *(const float4*)(src + e);
  ushort4 o;
  o.x = f2bf(v.x); o.y = f2bf(v.y); o.z = f2bf(v.z); o.w = f2bf(v.w);
  *(ushort4*)(dst + (rofs + (size_t)n) * 4096 + ofs + k) = o;
}

// ---- 256x256-tile LSTM GEMM, 32x32x16 MFMA (2382 TF ceiling, half the
// instruction count), r8's proven depth-4 ring / lead-3 / drain-before-barrier.
// 8 waves = 4M x 2N; wave = 64M x 128N-packed (4 gates x 32 j -> thread-local gates).
__global__ __launch_bounds__(512, 2) void lstm_gemm32(
    const unsigned short* __restrict__ Abf, const unsigned short* __restrict__ Wbf,
    const float* __restrict__ c_in,
    const float* __restrict__ bias_i, const float* __restrict__ bias_f,
    const float* __restrict__ bias_g, const float* __restrict__ bias_o,
    float* __restrict__ out) {
  __shared__ unsigned short lds[4 * 16384];   // 4 regions x 32KB = 128KB

  int tid = threadIdx.x;
  int lane = tid & 63;
  int wid = tid >> 6;            // 0..7
  int wr = wid >> 1;             // 0..3: M-group of 64 rows
  int wc = wid & 1;              // 0..1: N-group of 128 packed prows
  int l31 = lane & 31;
  int hi = lane >> 5;

  int bid = blockIdx.x;          // 512 blocks = 16 mt x 32 bn
  int xcd = bid & 7;
  int t7 = bid >> 3;
  int mt = t7 & 15;
  int bn = xcd * 4 + (t7 >> 4);  // each XCD owns 4 bn columns
  int m0 = mt * 256;

  // ---- staging sources: r0 = tid>>2 (0..127), cc0 = tid&3 (64B rows, 4 chunks)
  int r0 = tid >> 2, cc0 = tid & 3;
  int ccs0 = cc0 ^ ((r0 >> 1) & 3);           // inverse swizzle; invariant under +128 rows
  const unsigned short* pA = Abf + (size_t)(m0 + r0) * 4096 + ccs0 * 8;
  // B prow r0 (wc=0): Wbf row = (r0>>5)*2048 + bn*64 + (r0&31); prow r0+128: +32 rows
  const unsigned short* pB = Wbf + ((size_t)(r0 >> 5) * 2048 + bn * 64 + (r0 & 31)) * 4096 + ccs0 * 8;

  char* L0 = (char*)&lds[0];
  char* dD = L0 + tid * 16;
  unsigned ldsOff = (unsigned)(size_t)(__attribute__((address_space(3))) char*)L0;

  // ---- read addresses: key = (l31>>1)&3; chunk(kstep,hi) = (kstep*2+hi)^key
  unsigned key = ((unsigned)l31 >> 1) & 3u;
  unsigned ch0 = ((unsigned)hi ^ key) << 4;    // kstep0 chunk bytes; kstep1 = ^32
  unsigned adrA = ldsOff + (unsigned)(wr * 64 + l31) * 64 + ch0;
  unsigned adrB = ldsOff + 16384u + (unsigned)(wc * 128 + l31) * 64 + ch0;

  f32x16 acc[2][4];
  #pragma unroll
  for (int a = 0; a < 2; a++)
    #pragma unroll
    for (int b = 0; b < 4; b++)
      #pragma unroll
      for (int e = 0; e < 16; e++) acc[a][b][e] = 0.f;

  bf16x8 aA[4], bA[8], aB[4], bB[8];

  int o_n = 32768;               // region of group c+1 (init: g1)
  int o_s = 98304;               // region of group c+3 (init: g3)
  int koff = 96;                 // k-offset (elems) of group c+3

  // ---- prologue: stage g0,g1,g2; drain g0; read g0 -> set A
  STAGE_G(0, 0);
  STAGE_G(32, 32768);
  STAGE_G(64, 65536);
  WAITV(8);
  SBAR();
  { int sv = o_n; o_n = 0; RD12(aA, bA); o_n = sv; }

  // ---- main: slots 0..123 (stage g3..g126)
  for (int i = 0; i < 62; ++i) {
    SLOT(WAITV(4), STAGE_G(koff, o_s), aA, bA, aB, bB);   // even: MFMA A, read B
    SLOT(WAITV(4), STAGE_G(koff, o_s), aB, bB, aA, bA);   // odd:  MFMA B, read A
  }
  // slot 124 (even): stage g127
  SLOT(WAITV(4), STAGE_G(koff, o_s), aA, bA, aB, bB);
  // slot 125 (odd): no stage; drain g126
  SLOT(WAITV(4), (void)0, aB, bB, aA, bA);
  // slot 126 (even): drain g127, read it
  SLOT(WAITV(0), (void)0, aA, bA, aB, bB);
  // slot 127: final MFMA on set B (g127)
  WAITL(0);
  SCHED0();
  PRIO1(); MFMA16(aB, bB); PRIO0();

  // ---- epilogue: gates thread-local (frag index = gate); 32x32 C/D layout:
  // col = lane&31, row = (reg&3) + 8*(reg>>2) + 4*(lane>>5)   [verified m74/m101]
  int j = bn * 64 + wc * 32 + l31;
  float bi = bias_i[j], bff = bias_f[j], bgg = bias_g[j], bo = bias_o[j];
  int rb0 = m0 + wr * 64 + hi * 4;
  #pragma unroll
  for (int mf = 0; mf < 2; mf++) {
    #pragma unroll
    for (int reg = 0; reg < 16; reg++) {
      int m = rb0 + mf * 32 + (reg & 3) + 8 * (reg >> 2);
      size_t off = (size_t)m * HID + j;
      float gi = acc[mf][0][reg] + bi;
      float gf = acc[mf][1][reg] + bff;
      float gg = acc[mf][2][reg] + bgg;
      float go = acc[mf][3][reg] + bo;
      float iv = 1.f / (1.f + __expf(-gi));
      float fv = 1.f / (1.f + __expf(-gf));
      float gv = tanhf(gg);
      float ov = 1.f / (1.f + __expf(-go));
      float cn = fv * c_in[off] + iv * gv;
      float hn = ov * tanhf(cn);
      out[off] = hn;
      out[(size_t)BATCH * HID + off] = cn;
    }
  }
}

// ---- fallback (no workspace): round-3 verified 128-tile reg-staged kernel
__global__ __launch_bounds__(256) void lstm_gemm_fb(
    const float* __restrict__ x, const float* __restrict__ h,
    const float* __restrict__ wii, const float* __restrict__ wif,
    const float* __restrict__ wig, const float* __restrict__ wio,
    const float* __restrict__ whi, const float* __restrict__ whf,
    const float* __restrict__ whg, const float* __restrict__ who,
    const float* __restrict__ c_in,
    const float* __restrict__ bias_i, const float* __restrict__ bias_f,
    const float* __restrict__ bias_g, const float* __restrict__ bias_o,
    float* __restrict__ out) {
  __shared__ unsigned short Ald[128 * 64];
  __shared__ unsigned short Bld[128 * 64];
  int tid = threadIdx.x;
  int lane = tid & 63;
  int wid = tid >> 6;
  int wr = wid >> 1, wc = wid & 1;
  int bid = blockIdx.x;
  int swz = (bid & 7) * 256 + (bid >> 3);
  int mt = swz & 31;
  int ht = swz >> 5;
  int m0 = mt * 128;
  int j0 = ht * 32;
  f32x4 acc[4][4];
  #pragma unroll
  for (int a = 0; a < 4; a++)
    #pragma unroll
    for (int b = 0; b < 4; b++) acc[a][b] = (f32x4){0.f, 0.f, 0.f, 0.f};
  int lrow = lane & 15;
  int lsw = lrow & 7;
  int qbase = lane >> 4;
  for (int kt = 0; kt < 64; kt++) {
    int k0 = kt * 64;
    const float* Asrc = (k0 < 2048) ? x : h;
    int ka = k0 & 2047;
    #pragma unroll
    for (int i = 0; i < 4; i++) {
      int c = i * 256 + tid;
      int r = c >> 3, cc = c & 7;
      int ccs = cc ^ (r & 7);
      const float* s = Asrc + (size_t)(m0 + r) * 2048 + ka + ccs * 8;
      float4 v0 = *(const float4*)s;
      float4 v1 = *(const float4*)(s + 4);
      bf16x8 pk;
      pk[0] = (short)f2bf(v0.x); pk[1] = (short)f2bf(v0.y);
      pk[2] = (short)f2bf(v0.z); pk[3] = (short)f2bf(v0.w);
      pk[4] = (short)f2bf(v1.x); pk[5] = (short)f2bf(v1.y);
      pk[6] = (short)f2bf(v1.z); pk[7] = (short)f2bf(v1.w);
      *(bf16x8*)((char*)Ald + (size_t)c * 16) = pk;
    }
    #pragma unroll
    for (int i = 0; i < 4; i++) {
      int c = i * 256 + tid;
      int rb = c >> 3, cc = c & 7;
      int ccs = cc ^ (rb & 7);
      int g = rb >> 5, jj = rb & 31;
      const float* Bsrc;
      if (k0 < 2048) Bsrc = (g == 0) ? wii : (g == 1) ? wif : (g == 2) ? wig : wio;
      else           Bsrc = (g == 0) ? whi : (g == 1) ? whf : (g == 2) ? whg : who;
      const float* s = Bsrc + (size_t)(j0 + jj) * 2048 + ka + ccs * 8;
      float4 v0 = *(const float4*)s;
      float4 v1 = *(const float4*)(s + 4);
      bf16x8 pk;
      pk[0] = (short)f2bf(v0.x); pk[1] = (short)f2bf(v0.y);
      pk[2] = (short)f2bf(v0.z); pk[3] = (short)f2bf(v0.w);
      pk[4] = (short)f2bf(v1.x); pk[5] = (short)f2bf(v1.y);
      pk[6] = (short)f2bf(v1.z); pk[7] = (short)f2bf(v1.w);
      *(bf16x8*)((char*)Bld + (size_t)c * 16) = pk;
    }
    __syncthreads();
    #pragma unroll
    for (int ks = 0; ks < 2; ks++) {
      int q = ks * 4 + qbase;
      int qs8 = (q ^ lsw) * 8;
      bf16x8 af[4], bg[4];
      #pragma unroll
      for (int mf = 0; mf < 4; mf++)
        af[mf] = *(const bf16x8*)&Ald[(wr * 64 + mf * 16 + lrow) * 64 + qs8];
      #pragma unroll
      for (int g = 0; g < 4; g++)
        bg[g] = *(const bf16x8*)&Bld[(g * 32 + wc * 16 + lrow) * 64 + qs8];
      #pragma unroll
      for (int mf = 0; mf < 4; mf++)
        #pragma unroll
        for (int g = 0; g < 4; g++)
          acc[mf][g] = __builtin_amdgcn_mfma_f32_16x16x32_bf16(af[mf], bg[g], acc[mf][g], 0, 0, 0);
    }
    __syncthreads();
  }
  int j = j0 + wc * 16 + lrow;
  float bi = bias_i[j], bff = bias_f[j], bgg = bias_g[j], bo = bias_o[j];
  int rbase = m0 + wr * 64 + (lane >> 4) * 4;
  #pragma unroll
  for (int mf = 0; mf < 4; mf++) {
    #pragma unroll
    for (int q = 0; q < 4; q++) {
      int m = rbase + mf * 16 + q;
      size_t off = (size_t)m * HID + j;
      float gi = acc[mf][0][q] + bi;
      float gf = acc[mf][1][q] + bff;
      float gg = acc[mf][2][q] + bgg;
      float go = acc[mf][3][q] + bo;
      float iv = 1.f / (1.f + __expf(-gi));
      float fv = 1.f / (1.f + __expf(-gf));
      float gv = tanhf(gg);
      float ov = 1.f / (1.f + __expf(-go));
      float cn = fv * c_in[off] + iv * gv;
      float hn = ov * tanhf(cn);
      out[off] = hn;
      out[(size_t)BATCH * HID + off] = cn;
    }
  }
}

extern "C" void kernel_launch(void* const* d_in, const int* in_sizes, int n_in,
                              void* d_out, int out_size, void* d_ws, size_t ws_size,
                              hipStream_t stream) {
  const float* x   = (const float*)d_in[0];
  const float* h   = (const float*)d_in[1];
  const float* c   = (const float*)d_in[2];
  const float* wii = (const float*)d_in[3];
  const float* wif = (const float*)d_in[4];
  const float* wig = (const float*)d_in[5];
  const float* wio = (const float*)d_in[6];
  const float* whi = (const float*)d_in[7];
  const float* whf = (const float*)d_in[8];
  const float* whg = (const float*)d_in[9];
  const float* who = (const float*)d_in[10];
  const float* bi  = (const float*)d_in[11];
  const float* bf  = (const float*)d_in[12];
  const float* bg  = (const float*)d_in[13];
  const float* bo  = (const float*)d_in[14];
  float* out = (float*)d_out;

  size_t needA = (size_t)4096 * 4096 * 2;
  size_t needW = (size_t)8192 * 4096 * 2;

  if (ws_size >= needA + needW) {
    unsigned short* Abf = (unsigned short*)d_ws;
    unsigned short* Wbf = (unsigned short*)((char*)d_ws + needA);
    convert_kernel<<<dim3(4096, 12), 256, 0, stream>>>(
        x, h, wii, wif, wig, wio, whi, whf, whg, who, Abf, Wbf);
    lstm_gemm32<<<512, 512, 0, stream>>>(Abf, Wbf, c, bi, bf, bg, bo, out);
  } else {
    lstm_gemm_fb<<<2048, 256, 0, stream>>>(
        x, h, wii, wif, wig, wio, whi, whf, whg, who,
        c, bi, bf, bg, bo, out);
  }
}

// Round 14
// 318.656 us; speedup vs baseline: 1.0957x; 1.0957x over previous
//
#include <hip/hip_runtime.h>
#include <cstdint>
#include <cstddef>

#define BATCH 4096
#define HID   2048

typedef __attribute__((ext_vector_type(8))) short bf16x8;
typedef __attribute__((ext_vector_type(4))) float f32x4;

__device__ __forceinline__ unsigned short f2bf(float f) {
  union { float f; unsigned u; } a; a.f = f;
  unsigned u = a.u;
  return (unsigned short)((u + 0x7FFFu + ((u >> 16) & 1u)) >> 16);  // RNE
}

__device__ __forceinline__ void gload_lds16(const void* g, void* l) {
  __builtin_amdgcn_global_load_lds((const __attribute__((address_space(1))) void*)g,
                                   (__attribute__((address_space(3))) void*)l, 16, 0, 0);
}

#define SCHED0() __builtin_amdgcn_sched_barrier(0)
#define SBAR()  do { SCHED0(); __builtin_amdgcn_s_barrier(); SCHED0(); } while (0)
#define WAITV(N) do { SCHED0(); asm volatile("s_waitcnt vmcnt(" #N ")" ::: "memory"); SCHED0(); } while (0)
#define WAITL(N) do { SCHED0(); asm volatile("s_waitcnt lgkmcnt(" #N ")" ::: "memory"); SCHED0(); } while (0)
#define DSR(dst, adr, IMM) asm volatile("ds_read_b128 %0, %1 offset:" #IMM : "=v"(dst) : "v"(adr))
#define PRIO1() __builtin_amdgcn_s_setprio(1)
#define PRIO0() __builtin_amdgcn_s_setprio(0)

// 12 ds_read_b128 for one 32-K group: A M-half0 (a1), B (bf_), A M-half1 (a2)
#define READ_CLUSTER(AADR, BADR) do { \
  DSR(a1[0], (AADR), 0); DSR(a1[1], (AADR), 1024); DSR(a1[2], (AADR), 2048); DSR(a1[3], (AADR), 3072); \
  DSR(bf_[0], (BADR), 0); DSR(bf_[1], (BADR), 1024); DSR(bf_[2], (BADR), 2048); DSR(bf_[3], (BADR), 3072); \
  DSR(a2[0], (AADR), 4096); DSR(a2[1], (AADR), 5120); DSR(a2[2], (AADR), 6144); DSR(a2[3], (AADR), 7168); \
} while (0)

#define MFMA_HALF(AF, OFS) do { \
  _Pragma("unroll") \
  for (int m_ = 0; m_ < 4; m_++) { \
    _Pragma("unroll") \
    for (int n_ = 0; n_ < 4; n_++) \
      acc[(OFS) + m_][n_] = __builtin_amdgcn_mfma_f32_16x16x32_bf16(AF[m_], bf_[n_], acc[(OFS) + m_][n_], 0, 0, 0); \
  } \
} while (0)

// stage one 32KB group (A 256x32K 16KB + B 256x32K 16KB) at region offset DOF
#define STAGE_G(KOFF, DOF) do { \
  gload_lds16(pA + (KOFF), dA + (DOF)); \
  gload_lds16(pA + 128 * 4096 + (KOFF), dA + (DOF) + 8192); \
  gload_lds16(pB + (KOFF), dA + (DOF) + 16384); \
  gload_lds16(pB + 32 * 4096 + (KOFF), dA + (DOF) + 24576); } while (0)

#define ADV2(o) do { (o) += 65536; if ((o) >= 163840) (o) -= 163840; } while (0)

// one interval: 2 groups per barrier. Drain own stages (vmcnt 0), barrier,
// then per group: 12 reads + 1 stage-group, lgkm(0), 32 MFMA.
#define INTERVAL(STG1, STG2) do { \
  WAITV(0); \
  SBAR(); \
  READ_CLUSTER(aB0 + (unsigned)o_a, bB0 + (unsigned)o_a); \
  STG1; \
  WAITL(0); \
  PRIO1(); MFMA_HALF(a1, 0); MFMA_HALF(a2, 4); PRIO0(); \
  READ_CLUSTER(aB0 + (unsigned)o_b, bB0 + (unsigned)o_b); \
  STG2; \
  WAITL(0); \
  PRIO1(); MFMA_HALF(a1, 0); MFMA_HALF(a2, 4); PRIO0(); \
  ADV2(o_a); ADV2(o_b); ADV2(o_s1); ADV2(o_s2); ks += 64; \
} while (0)

// ---- fp32 -> bf16 pack (verified r2): A=[x|h] 4096x4096; Wbf gate-major 8192x4096
__global__ __launch_bounds__(256) void convert_kernel(
    const float* __restrict__ x, const float* __restrict__ h,
    const float* __restrict__ wii, const float* __restrict__ wif,
    const float* __restrict__ wig, const float* __restrict__ wio,
    const float* __restrict__ whi, const float* __restrict__ whf,
    const float* __restrict__ whg, const float* __restrict__ who,
    unsigned short* __restrict__ Abf, unsigned short* __restrict__ Wbf) {
  int seg = blockIdx.y;
  const float* src;
  unsigned short* dst;
  int ofs;
  size_t rofs;
  if (seg < 4) {
    src = (seg < 2) ? x : h;
    dst = Abf;
    ofs = (seg < 2) ? 0 : 2048;
    rofs = (seg & 1) ? 2048 : 0;
    src += rofs * 2048;
  } else {
    int g = (seg - 4) & 3;
    dst = Wbf + (size_t)g * 2048 * 4096;
    ofs = (seg >= 8) ? 2048 : 0;
    rofs = 0;
    switch (seg) {
      case 4: src = wii; break; case 5: src = wif; break;
      case 6: src = wig; break; case 7: src = wio; break;
      case 8: src = whi; break; case 9: src = whf; break;
      case 10: src = whg; break; default: src = who; break;
    }
  }
  size_t idx = (size_t)blockIdx.x * 256 + threadIdx.x;
  size_t e = idx * 4;
  int n = (int)(e >> 11);
  int k = (int)(e & 2047);
  float4 v = *(const float4*)(src + e);
  ushort4 o;
  o.x = f2bf(v.x); o.y = f2bf(v.y); o.z = f2bf(v.z); o.w = f2bf(v.w);
  *(ushort4*)(dst + (rofs + (size_t)n) * 4096 + ofs + k) = o;
}

// ---- 256x256-tile LSTM GEMM, depth-5 ring (160KB), 2 groups per barrier
// (64 barriers + 64 vmcnt total), r8's layout/swizzle/epilogue (verified).
__global__ __launch_bounds__(512, 2) void lstm_gemm8(
    const unsigned short* __restrict__ Abf, const unsigned short* __restrict__ Wbf,
    const float* __restrict__ c_in,
    const float* __restrict__ bias_i, const float* __restrict__ bias_f,
    const float* __restrict__ bias_g, const float* __restrict__ bias_o,
    float* __restrict__ out) {
  __shared__ unsigned short lds[5 * 16384];   // 5 regions x 32KB = 160KB

  int tid = threadIdx.x;
  int lane = tid & 63;
  int wid = tid >> 6;            // 0..7
  int wr = wid >> 2;             // M-half (128 rows)
  int wc = wid & 3;              // N-quarter (64 packed prows)
  int lrow = lane & 15;
  int qh = lane >> 4;            // 16B chunk within 32-k group

  int bid = blockIdx.x;          // 512 blocks = 16 mt x 32 bn
  int xcd = bid & 7;
  int t7 = bid >> 3;
  int mt = t7 & 15;
  int bn = xcd * 4 + (t7 >> 4);  // each XCD owns 4 bn columns
  int m0 = mt * 256;

  // staging source addresses (linear LDS dest; inverse-swizzled global chunk)
  int r0 = tid >> 2, cc0 = tid & 3;
  int ccs0 = cc0 ^ ((r0 >> 1) & 3);
  const unsigned short* pA = Abf + (size_t)(m0 + r0) * 4096 + ccs0 * 8;
  int g0 = (r0 >> 4) & 3;
  int jw = bn * 64 + ((r0 >> 6) & 3) * 16 + (r0 & 15);
  const unsigned short* pB = Wbf + ((size_t)g0 * 2048 + jw) * 4096 + ccs0 * 8;

  char* L0 = (char*)&lds[0];
  char* dA = L0 + tid * 16;
  unsigned ldsOff = (unsigned)(size_t)(__attribute__((address_space(3))) char*)L0;

  int arow0 = wr * 128 + lrow;
  int brow0 = wc * 64 + lrow;
  unsigned qsA = ((unsigned)(qh ^ ((arow0 >> 1) & 3))) << 4;
  unsigned qsB = ((unsigned)(qh ^ ((brow0 >> 1) & 3))) << 4;
  unsigned aB0 = ldsOff + (unsigned)arow0 * 64 + qsA;            // + region offset
  unsigned bB0 = ldsOff + 16384u + (unsigned)brow0 * 64 + qsB;   // + region offset

  f32x4 acc[8][4];
  #pragma unroll
  for (int a = 0; a < 8; a++)
    #pragma unroll
    for (int b = 0; b < 4; b++) acc[a][b] = (f32x4){0.f, 0.f, 0.f, 0.f};

  bf16x8 a1[4], a2[4], bf_[4];

  // region byte-offsets: groups a=2t, b=2t+1, stage targets 2t+2, 2t+3 (mod-5 ring)
  int o_a = 0, o_b = 32768, o_s1 = 65536, o_s2 = 98304;
  int ks = 64;                   // k-offset (elems) of group 2t+2

  // ---- prologue: stage g0 (region 0), g1 (region 1)
  STAGE_G(0, 0);
  STAGE_G(32, 32768);

  // ---- main: intervals t=0..62 (stage groups 2..127)
  for (int t = 0; t < 63; ++t) {
    INTERVAL(STAGE_G(ks, o_s1), STAGE_G(ks + 32, o_s2));
  }
  // ---- tail interval t=63: groups 126,127; no staging
  INTERVAL((void)0, (void)0);

  // ---- epilogue: all 4 gates (n-index) for (m, j) are thread-local
  int j = bn * 64 + wc * 16 + lrow;
  float bi = bias_i[j], bff = bias_f[j], bgg = bias_g[j], bo = bias_o[j];
  int rbase = m0 + wr * 128 + qh * 4;
  #pragma unroll
  for (int mf = 0; mf < 8; mf++) {
    #pragma unroll
    for (int qq = 0; qq < 4; qq++) {
      int m = rbase + mf * 16 + qq;     // C/D: col=lane&15, row=(lane>>4)*4+qq
      size_t off = (size_t)m * HID + j;
      float gi = acc[mf][0][qq] + bi;
      float gf = acc[mf][1][qq] + bff;
      float gg = acc[mf][2][qq] + bgg;
      float go = acc[mf][3][qq] + bo;
      float iv = 1.f / (1.f + __expf(-gi));
      float fv = 1.f / (1.f + __expf(-gf));
      float gv = tanhf(gg);
      float ov = 1.f / (1.f + __expf(-go));
      float cn = fv * c_in[off] + iv * gv;
      float hn = ov * tanhf(cn);
      out[off] = hn;
      out[(size_t)BATCH * HID + off] = cn;
    }
  }
}

// ---- fallback (no workspace): round-3 verified 128-tile reg-staged kernel
__global__ __launch_bounds__(256) void lstm_gemm_fb(
    const float* __restrict__ x, const float* __restrict__ h,
    const float* __restrict__ wii, const float* __restrict__ wif,
    const float* __restrict__ wig, const float* __restrict__ wio,
    const float* __restrict__ whi, const float* __restrict__ whf,
    const float* __restrict__ whg, const float* __restrict__ who,
    const float* __restrict__ c_in,
    const float* __restrict__ bias_i, const float* __restrict__ bias_f,
    const float* __restrict__ bias_g, const float* __restrict__ bias_o,
    float* __restrict__ out) {
  __shared__ unsigned short Ald[128 * 64];
  __shared__ unsigned short Bld[128 * 64];
  int tid = threadIdx.x;
  int lane = tid & 63;
  int wid = tid >> 6;
  int wr = wid >> 1, wc = wid & 1;
  int bid = blockIdx.x;
  int swz = (bid & 7) * 256 + (bid >> 3);
  int mt = swz & 31;
  int ht = swz >> 5;
  int m0 = mt * 128;
  int j0 = ht * 32;
  f32x4 acc[4][4];
  #pragma unroll
  for (int a = 0; a < 4; a++)
    #pragma unroll
    for (int b = 0; b < 4; b++) acc[a][b] = (f32x4){0.f, 0.f, 0.f, 0.f};
  int lrow = lane & 15;
  int lsw = lrow & 7;
  int qbase = lane >> 4;
  for (int kt = 0; kt < 64; kt++) {
    int k0 = kt * 64;
    const float* Asrc = (k0 < 2048) ? x : h;
    int ka = k0 & 2047;
    #pragma unroll
    for (int i = 0; i < 4; i++) {
      int c = i * 256 + tid;
      int r = c >> 3, cc = c & 7;
      int ccs = cc ^ (r & 7);
      const float* s = Asrc + (size_t)(m0 + r) * 2048 + ka + ccs * 8;
      float4 v0 = *(const float4*)s;
      float4 v1 = *(const float4*)(s + 4);
      bf16x8 pk;
      pk[0] = (short)f2bf(v0.x); pk[1] = (short)f2bf(v0.y);
      pk[2] = (short)f2bf(v0.z); pk[3] = (short)f2bf(v0.w);
      pk[4] = (short)f2bf(v1.x); pk[5] = (short)f2bf(v1.y);
      pk[6] = (short)f2bf(v1.z); pk[7] = (short)f2bf(v1.w);
      *(bf16x8*)((char*)Ald + (size_t)c * 16) = pk;
    }
    #pragma unroll
    for (int i = 0; i < 4; i++) {
      int c = i * 256 + tid;
      int rb = c >> 3, cc = c & 7;
      int ccs = cc ^ (rb & 7);
      int g = rb >> 5, jj = rb & 31;
      const float* Bsrc;
      if (k0 < 2048) Bsrc = (g == 0) ? wii : (g == 1) ? wif : (g == 2) ? wig : wio;
      else           Bsrc = (g == 0) ? whi : (g == 1) ? whf : (g == 2) ? whg : who;
      const float* s = Bsrc + (size_t)(j0 + jj) * 2048 + ka + ccs * 8;
      float4 v0 = *(const float4*)s;
      float4 v1 = *(const float4*)(s + 4);
      bf16x8 pk;
      pk[0] = (short)f2bf(v0.x); pk[1] = (short)f2bf(v0.y);
      pk[2] = (short)f2bf(v0.z); pk[3] = (short)f2bf(v0.w);
      pk[4] = (short)f2bf(v1.x); pk[5] = (short)f2bf(v1.y);
      pk[6] = (short)f2bf(v1.z); pk[7] = (short)f2bf(v1.w);
      *(bf16x8*)((char*)Bld + (size_t)c * 16) = pk;
    }
    __syncthreads();
    #pragma unroll
    for (int ks = 0; ks < 2; ks++) {
      int q = ks * 4 + qbase;
      int qs8 = (q ^ lsw) * 8;
      bf16x8 af[4], bg[4];
      #pragma unroll
      for (int mf = 0; mf < 4; mf++)
        af[mf] = *(const bf16x8*)&Ald[(wr * 64 + mf * 16 + lrow) * 64 + qs8];
      #pragma unroll
      for (int g = 0; g < 4; g++)
        bg[g] = *(const bf16x8*)&Bld[(g * 32 + wc * 16 + lrow) * 64 + qs8];
      #pragma unroll
      for (int mf = 0; mf < 4; mf++)
        #pragma unroll
        for (int g = 0; g < 4; g++)
          acc[mf][g] = __builtin_amdgcn_mfma_f32_16x16x32_bf16(af[mf], bg[g], acc[mf][g], 0, 0, 0);
    }
    __syncthreads();
  }
  int j = j0 + wc * 16 + lrow;
  float bi = bias_i[j], bff = bias_f[j], bgg = bias_g[j], bo = bias_o[j];
  int rbase = m0 + wr * 64 + (lane >> 4) * 4;
  #pragma unroll
  for (int mf = 0; mf < 4; mf++) {
    #pragma unroll
    for (int q = 0; q < 4; q++) {
      int m = rbase + mf * 16 + q;
      size_t off = (size_t)m * HID + j;
      float gi = acc[mf][0][q] + bi;
      float gf = acc[mf][1][q] + bff;
      float gg = acc[mf][2][q] + bgg;
      float go = acc[mf][3][q] + bo;
      float iv = 1.f / (1.f + __expf(-gi));
      float fv = 1.f / (1.f + __expf(-gf));
      float gv = tanhf(gg);
      float ov = 1.f / (1.f + __expf(-go));
      float cn = fv * c_in[off] + iv * gv;
      float hn = ov * tanhf(cn);
      out[off] = hn;
      out[(size_t)BATCH * HID + off] = cn;
    }
  }
}

extern "C" void kernel_launch(void* const* d_in, const int* in_sizes, int n_in,
                              void* d_out, int out_size, void* d_ws, size_t ws_size,
                              hipStream_t stream) {
  const float* x   = (const float*)d_in[0];
  const float* h   = (const float*)d_in[1];
  const float* c   = (const float*)d_in[2];
  const float* wii = (const float*)d_in[3];
  const float* wif = (const float*)d_in[4];
  const float* wig = (const float*)d_in[5];
  const float* wio = (const float*)d_in[6];
  const float* whi = (const float*)d_in[7];
  const float* whf = (const float*)d_in[8];
  const float* whg = (const float*)d_in[9];
  const float* who = (const float*)d_in[10];
  const float* bi  = (const float*)d_in[11];
  const float* bf  = (const float*)d_in[12];
  const float* bg  = (const float*)d_in[13];
  const float* bo  = (const float*)d_in[14];
  float* out = (float*)d_out;

  size_t needA = (size_t)4096 * 4096 * 2;
  size_t needW = (size_t)8192 * 4096 * 2;

  if (ws_size >= needA + needW) {
    unsigned short* Abf = (unsigned short*)d_ws;
    unsigned short* Wbf = (unsigned short*)((char*)d_ws + needA);
    convert_kernel<<<dim3(4096, 12), 256, 0, stream>>>(
        x, h, wii, wif, wig, wio, whi, whf, whg, who, Abf, Wbf);
    lstm_gemm8<<<512, 512, 0, stream>>>(Abf, Wbf, c, bi, bf, bg, bo, out);
  } else {
    lstm_gemm_fb<<<2048, 256, 0, stream>>>(
        x, h, wii, wif, wig, wio, whi, whf, whg, who,
        c, bi, bf, bg, bo, out);
  }
}